// Round 16
// baseline (136.985 us; speedup 1.0000x reference)
//
#include <hip/hip_runtime.h>
#include <hip/hip_bf16.h>
#include <math.h>

typedef __bf16 bf16_t;
typedef bf16_t bf16x8 __attribute__((ext_vector_type(8)));
typedef bf16_t bf16x4 __attribute__((ext_vector_type(4)));
typedef float f32x4 __attribute__((ext_vector_type(4)));

#define L_TEXT 2048
#define N_TOKEN 2048
#define C_TEXT 3584
#define C_OUT 384
#define C_HID 768
#define BATCH 8
#define MAXROWS (BATCH * N_TOKEN)
#define PM 3072            // capacity for compacted rows (count ~2400)
#define NPAIR (BATCH * 6)
#define KSPLIT 2
#define KCHUNK (C_TEXT / KSPLIT)   // 1792

#define NW1 (C_HID * C_TEXT / 8)          // 344064 W1 cvt chunks
#define NW2 (C_OUT * C_HID / 8)           // 36864  W2 cvt chunks
#define NZERO (MAXROWS * C_OUT / 4)       // 1572864 f32x4 zero chunks of d_out
#define CHUNKS_TOTAL (NW1 + NW2 + NZERO)
#define CHUNK_BLOCKS (CHUNKS_TOTAL / 256) // 7632 exactly
#define GCH (C_TEXT / 8)                  // 448 bf16x8 chunks per row

// ---------------------------------------------------------------------------
// scan node: 48 per-pair mask-scan blocks (tiny, heads the critical path)
__global__ __launch_bounds__(64) void scan_kernel(
    const int* __restrict__ tm, const int* __restrict__ ctid,
    const int* __restrict__ cdrid, const int* __restrict__ bct,
    const int* __restrict__ brt,
    int* __restrict__ trowL, int* __restrict__ pidxL, int* __restrict__ vcnt) {
    const int bp = blockIdx.x;
    const int lane = threadIdx.x;
    const int b = bp / 6, p = bp % 6;
    const int ct = (p < 3) ? 1 : 2;
    const int rt = 2 + 2 * (p % 3);
    const unsigned long long ltm = (1ull << lane) - 1ull;

    unsigned int tbits = 0, pbits = 0;
#pragma unroll
    for (int i = 0; i < 32; i++) {
        int l = i * 64 + lane;
        unsigned int m = (ctid[b * L_TEXT + l] == ct) &&
                         (cdrid[b * L_TEXT + l] == rt) &&
                         (tm[b * L_TEXT + l] != 0);
        tbits |= m << i;
    }
#pragma unroll
    for (int i = 0; i < 32; i++) {
        int n = i * 64 + lane;
        unsigned int m = (bct[b * N_TOKEN + n] == ct) &&
                         (brt[b * N_TOKEN + n] == rt);
        pbits |= m << i;
    }
    int base = 0;
#pragma unroll
    for (int i = 0; i < 32; i++) {
        bool m = (tbits >> i) & 1;
        unsigned long long bal = __ballot(m);
        if (m) trowL[bp * L_TEXT + base + __popcll(bal & ltm)] = i * 64 + lane;
        base += __popcll(bal);
    }
    const int n_text = base;
    base = 0;
#pragma unroll
    for (int i = 0; i < 32; i++) {
        bool m = (pbits >> i) & 1;
        unsigned long long bal = __ballot(m);
        if (m) pidxL[bp * L_TEXT + base + __popcll(bal & ltm)] = i * 64 + lane;
        base += __popcll(bal);
    }
    const int n_prot = base;
    if (lane == 0) vcnt[bp] = n_text < n_prot ? n_text : n_prot;
}

// ---------------------------------------------------------------------------
// prep node: cvt W1/W2 + zero d_out concurrent with wide map+gather.
__global__ __launch_bounds__(256) void prep_kernel(
    const float* __restrict__ W1, const float* __restrict__ W2,
    bf16_t* __restrict__ W1b, bf16_t* __restrict__ W2b,
    float* __restrict__ outp,
    const float* __restrict__ X,
    const int* __restrict__ trowL, const int* __restrict__ pidxL,
    const int* __restrict__ vcnt,
    int* __restrict__ rows_dst, int* __restrict__ count,
    bf16_t* __restrict__ Xg) {
    const int t = threadIdx.x;
    if (blockIdx.x < CHUNK_BLOCKS) {
        int idx = blockIdx.x * 256 + t;
        if (idx < NW1) {
            int i = idx * 8;
            float4 v0 = *(const float4*)(W1 + i);
            float4 v1 = *(const float4*)(W1 + i + 4);
            bf16x8 o;
            o[0] = (bf16_t)v0.x; o[1] = (bf16_t)v0.y; o[2] = (bf16_t)v0.z; o[3] = (bf16_t)v0.w;
            o[4] = (bf16_t)v1.x; o[5] = (bf16_t)v1.y; o[6] = (bf16_t)v1.z; o[7] = (bf16_t)v1.w;
            *(bf16x8*)(W1b + i) = o;
        } else if (idx < NW1 + NW2) {
            int i = (idx - NW1) * 8;
            float4 v0 = *(const float4*)(W2 + i);
            float4 v1 = *(const float4*)(W2 + i + 4);
            bf16x8 o;
            o[0] = (bf16_t)v0.x; o[1] = (bf16_t)v0.y; o[2] = (bf16_t)v0.z; o[3] = (bf16_t)v0.w;
            o[4] = (bf16_t)v1.x; o[5] = (bf16_t)v1.y; o[6] = (bf16_t)v1.z; o[7] = (bf16_t)v1.w;
            *(bf16x8*)(W2b + i) = o;
        } else {
            int z = idx - NW1 - NW2;
            f32x4 zv = (f32x4){0.f, 0.f, 0.f, 0.f};
            *(f32x4*)(outp + (size_t)z * 4) = zv;
        }
        return;
    }

    // ---- wide map+gather: one block per compacted row m ----
    __shared__ int vc[NPAIR];
    const int m = blockIdx.x - CHUNK_BLOCKS;
    if (t < NPAIR) vc[t] = vcnt[t];
    __syncthreads();

    int base = 0, bp = -1, total = 0;
    for (int q = 0; q < NPAIR; q++) {
        int v = vc[q];
        if (bp < 0 && m < base + v) bp = q;       // first pair containing m
        if (bp < 0) base += v;
        total += v;
    }
    if (m == 0 && t == 0) *count = total < PM ? total : PM;
    if (bp < 0 || m >= PM) return;                // m beyond total rows
    const int r = m - base;
    const int b = bp / 6;

    if (t == 0) rows_dst[m] = b * N_TOKEN + pidxL[bp * L_TEXT + r];

    const int src = b * L_TEXT + trowL[bp * L_TEXT + r];
    const float* s = X + (size_t)src * C_TEXT;
    bf16_t* d = Xg + (size_t)m * C_TEXT;
    for (int c = t; c < GCH; c += 256) {
        int i = c * 8;
        float4 v0 = *(const float4*)(s + i);
        float4 v1 = *(const float4*)(s + i + 4);
        bf16x8 o;
        o[0] = (bf16_t)v0.x; o[1] = (bf16_t)v0.y; o[2] = (bf16_t)v0.z; o[3] = (bf16_t)v0.w;
        o[4] = (bf16_t)v1.x; o[5] = (bf16_t)v1.y; o[6] = (bf16_t)v1.z; o[7] = (bf16_t)v1.w;
        *(bf16x8*)(d + i) = o;
    }
}

// ---------------------------------------------------------------------------
// GEMM1 (split-K=2, BM=32): P[ks][m][n] = sum_{k chunk} Xg[m][k]*W1[n][k]
// 32x128 tile, BK=32, 4 waves (1x4), wave tile 32x32, reg-staged dbuf LDS.
// 1152 blocks (~4.5/CU active) — highest-TLP gemm1 config; structure is
// gemm2's proven inner loop with a k-chunk offset.
__global__ __launch_bounds__(256) void gemm1_kernel(
    const bf16_t* __restrict__ Xg, const bf16_t* __restrict__ W1b,
    const int* __restrict__ countp, float* __restrict__ P) {
    int count = *countp; if (count > PM) count = PM;
    const int m0 = blockIdx.x * 32;
    if (m0 >= count) return;
    const int n0 = blockIdx.y * 128;
    const int kbeg = blockIdx.z * KCHUNK;

    __shared__ __align__(16) bf16_t As[2][32][40];
    __shared__ __align__(16) bf16_t Bs[2][128][40];

    const int t = threadIdx.x;
    const int lane = t & 63;
    const int w = t >> 6;              // wave n-offset = w*32
    const int fr = lane & 15;
    const int kq = (lane >> 4) * 8;

    f32x4 acc[2][2];
#pragma unroll
    for (int i = 0; i < 2; i++)
#pragma unroll
        for (int j = 0; j < 2; j++) acc[i][j] = (f32x4){0.f, 0.f, 0.f, 0.f};

    // A: 32x32 = 128 chunks (threads 0-127); B: 128x32 = 512 chunks (2/thread)
    const int arow = t >> 2, ac8 = (t & 3) * 8;
    const bool astage = (t < 128);
    const bf16_t* ap = Xg + (size_t)(m0 + arow) * C_TEXT + kbeg + ac8;  // stale rows harmless
    const int aofs = arow * 40 + ac8;
    const bf16_t* bp[2];
    int bofs[2];
#pragma unroll
    for (int j = 0; j < 2; j++) {
        int c = t + 256 * j;
        int row = c >> 2, c8 = (c & 3) * 8;
        bp[j] = W1b + (size_t)(n0 + row) * C_TEXT + kbeg + c8;
        bofs[j] = row * 40 + c8;
    }

    bf16_t* AsF = &As[0][0][0];
    bf16_t* BsF = &Bs[0][0][0];
    const int ABUF = 32 * 40, BBUF = 128 * 40;

    bf16x8 ra;
    if (astage) ra = *(const bf16x8*)(ap);
    bf16x8 rb0 = *(const bf16x8*)(bp[0]);
    bf16x8 rb1 = *(const bf16x8*)(bp[1]);

    const int T = KCHUNK / 32;   // 56
    for (int tile = 0; tile < T; ++tile) {
        const int cur = tile & 1;
        if (astage) *(bf16x8*)(AsF + cur * ABUF + aofs) = ra;
        *(bf16x8*)(BsF + cur * BBUF + bofs[0]) = rb0;
        *(bf16x8*)(BsF + cur * BBUF + bofs[1]) = rb1;
        bf16x8 na, nb0, nb1;
        bool more = (tile + 1 < T);
        if (more) {
            int k = (tile + 1) * 32;
            if (astage) na = *(const bf16x8*)(ap + k);
            nb0 = *(const bf16x8*)(bp[0] + k);
            nb1 = *(const bf16x8*)(bp[1] + k);
        }
        __syncthreads();
        bf16x8 af[2], bfr[2];
#pragma unroll
        for (int mi = 0; mi < 2; mi++)
            af[mi] = *(const bf16x8*)(AsF + cur * ABUF + (mi * 16 + fr) * 40 + kq);
#pragma unroll
        for (int ni = 0; ni < 2; ni++)
            bfr[ni] = *(const bf16x8*)(BsF + cur * BBUF + (w * 32 + ni * 16 + fr) * 40 + kq);
#pragma unroll
        for (int mi = 0; mi < 2; mi++)
#pragma unroll
            for (int ni = 0; ni < 2; ni++)
                acc[mi][ni] = __builtin_amdgcn_mfma_f32_16x16x32_bf16(
                    af[mi], bfr[ni], acc[mi][ni], 0, 0, 0);
        if (more) { if (astage) ra = na; rb0 = nb0; rb1 = nb1; }
        __syncthreads();
    }

    float* Pk = P + (size_t)blockIdx.z * PM * C_HID;
    const int rj = (lane >> 4) * 4;
#pragma unroll
    for (int mi = 0; mi < 2; mi++) {
#pragma unroll
        for (int ni = 0; ni < 2; ni++) {
            int gn = n0 + w * 32 + ni * 16 + fr;
#pragma unroll
            for (int j = 0; j < 4; j++) {
                int gm = m0 + mi * 16 + rj + j;
                if (gm < count) Pk[(size_t)gm * C_HID + gn] = acc[mi][ni][j];
            }
        }
    }
}

// ---------------------------------------------------------------------------
// reduce partials + bias + SiLU -> H (bf16)
__global__ __launch_bounds__(256) void reduce1_kernel(
    const float* __restrict__ P, const float* __restrict__ b1,
    const int* __restrict__ countp, bf16_t* __restrict__ H) {
    int count = *countp; if (count > PM) count = PM;
    int idx = blockIdx.x * 256 + threadIdx.x;
    int m = idx / (C_HID / 4);
    int c = (idx % (C_HID / 4)) * 4;
    if (m >= count) return;
    f32x4 s = *(const f32x4*)(P + (size_t)m * C_HID + c);
#pragma unroll
    for (int ks = 1; ks < KSPLIT; ks++)
        s += *(const f32x4*)(P + ((size_t)ks * PM + m) * C_HID + c);
    f32x4 bb = *(const f32x4*)(b1 + c);
    bf16x4 o;
#pragma unroll
    for (int j = 0; j < 4; j++) {
        float v = s[j] + bb[j];
        o[j] = (bf16_t)(v / (1.0f + __expf(-v)));
    }
    *(bf16x4*)(H + (size_t)m * C_HID + c) = o;
}

// ---------------------------------------------------------------------------
// GEMM2 fused: out[rows_dst[m]][n] = scale*(sum_K H[m][k]*W2[n][k] + b2[n])
// 32x128 tile, BK=32, 4 waves (1x4), wave tile 32x32, dbuf LDS. (proven)
__global__ __launch_bounds__(256) void gemm2_kernel(
    const bf16_t* __restrict__ Hm, const bf16_t* __restrict__ W2b,
    const float* __restrict__ b2, const int* __restrict__ rows_dst,
    const int* __restrict__ countp, const float* __restrict__ scale,
    float* __restrict__ outp) {
    int count = *countp; if (count > PM) count = PM;
    const int m0 = blockIdx.x * 32;
    if (m0 >= count) return;
    const int n0 = blockIdx.y * 128;

    __shared__ __align__(16) bf16_t As[2][32][40];
    __shared__ __align__(16) bf16_t Bs[2][128][40];

    const int t = threadIdx.x;
    const int lane = t & 63;
    const int w = t >> 6;              // wave n-offset = w*32
    const int fr = lane & 15;
    const int kq = (lane >> 4) * 8;

    f32x4 acc[2][2];
#pragma unroll
    for (int i = 0; i < 2; i++)
#pragma unroll
        for (int j = 0; j < 2; j++) acc[i][j] = (f32x4){0.f, 0.f, 0.f, 0.f};

    const int arow = t >> 2, ac8 = (t & 3) * 8;
    const bool astage = (t < 128);
    const bf16_t* ap = Hm + (size_t)(m0 + arow) * C_HID + ac8;   // stale rows harmless
    const int aofs = arow * 40 + ac8;
    const bf16_t* bp[2];
    int bofs[2];
#pragma unroll
    for (int j = 0; j < 2; j++) {
        int c = t + 256 * j;
        int row = c >> 2, c8 = (c & 3) * 8;
        bp[j] = W2b + (size_t)(n0 + row) * C_HID + c8;
        bofs[j] = row * 40 + c8;
    }

    bf16_t* AsF = &As[0][0][0];
    bf16_t* BsF = &Bs[0][0][0];
    const int ABUF = 32 * 40, BBUF = 128 * 40;

    bf16x8 ra;
    if (astage) ra = *(const bf16x8*)(ap);
    bf16x8 rb0 = *(const bf16x8*)(bp[0]);
    bf16x8 rb1 = *(const bf16x8*)(bp[1]);

    const int T = C_HID / 32;   // 24
    for (int tile = 0; tile < T; ++tile) {
        const int cur = tile & 1;
        if (astage) *(bf16x8*)(AsF + cur * ABUF + aofs) = ra;
        *(bf16x8*)(BsF + cur * BBUF + bofs[0]) = rb0;
        *(bf16x8*)(BsF + cur * BBUF + bofs[1]) = rb1;
        bf16x8 na, nb0, nb1;
        bool more = (tile + 1 < T);
        if (more) {
            int k = (tile + 1) * 32;
            if (astage) na = *(const bf16x8*)(ap + k);
            nb0 = *(const bf16x8*)(bp[0] + k);
            nb1 = *(const bf16x8*)(bp[1] + k);
        }
        __syncthreads();
        bf16x8 af[2], bfr[2];
#pragma unroll
        for (int mi = 0; mi < 2; mi++)
            af[mi] = *(const bf16x8*)(AsF + cur * ABUF + (mi * 16 + fr) * 40 + kq);
#pragma unroll
        for (int ni = 0; ni < 2; ni++)
            bfr[ni] = *(const bf16x8*)(BsF + cur * BBUF + (w * 32 + ni * 16 + fr) * 40 + kq);
#pragma unroll
        for (int mi = 0; mi < 2; mi++)
#pragma unroll
            for (int ni = 0; ni < 2; ni++)
                acc[mi][ni] = __builtin_amdgcn_mfma_f32_16x16x32_bf16(
                    af[mi], bfr[ni], acc[mi][ni], 0, 0, 0);
        if (more) { if (astage) ra = na; rb0 = nb0; rb1 = nb1; }
        __syncthreads();
    }

    const float sc = scale[0];
    const int rj = (lane >> 4) * 4;
#pragma unroll
    for (int mi = 0; mi < 2; mi++) {
#pragma unroll
        for (int ni = 0; ni < 2; ni++) {
            int gn = n0 + w * 32 + ni * 16 + fr;
            float bias = b2[gn];
#pragma unroll
            for (int j = 0; j < 4; j++) {
                int gm = m0 + mi * 16 + rj + j;
                if (gm < count) {
                    int dst = rows_dst[gm];
                    outp[(size_t)dst * C_OUT + gn] = sc * (acc[mi][ni][j] + bias);
                }
            }
        }
    }
}

// ---------------------------------------------------------------------------
extern "C" void kernel_launch(void* const* d_in, const int* in_sizes, int n_in,
                              void* d_out, int out_size, void* d_ws, size_t ws_size,
                              hipStream_t stream) {
    const float* X     = (const float*)d_in[0];
    const int*   tm    = (const int*)d_in[1];
    const int*   ctid  = (const int*)d_in[2];
    const int*   cdrid = (const int*)d_in[3];
    const int*   bct   = (const int*)d_in[4];
    const int*   brt   = (const int*)d_in[5];
    const float* W1    = (const float*)d_in[6];
    const float* b1    = (const float*)d_in[7];
    const float* W2    = (const float*)d_in[8];
    const float* b2    = (const float*)d_in[9];
    const float* scale = (const float*)d_in[10];

    char* ws = (char*)d_ws;
    size_t off = 0;
    int* count = (int*)(ws + off);        off += 1024;
    int* vcnt = (int*)(ws + off);         off += 1024;
    int* rows_dst = (int*)(ws + off);     off += (size_t)PM * 4;
    int* trowL = (int*)(ws + off);        off += (size_t)NPAIR * L_TEXT * 4;
    int* pidxL = (int*)(ws + off);        off += (size_t)NPAIR * L_TEXT * 4;
    bf16_t* W1b = (bf16_t*)(ws + off);    off += (size_t)C_HID * C_TEXT * 2;
    bf16_t* W2b = (bf16_t*)(ws + off);    off += (size_t)C_OUT * C_HID * 2;
    bf16_t* Xg = (bf16_t*)(ws + off);     off += (size_t)PM * C_TEXT * 2;
    bf16_t* H = (bf16_t*)(ws + off);      off += (size_t)PM * C_HID * 2;
    float* P = (float*)(ws + off);        off += (size_t)KSPLIT * PM * C_HID * 4;
    float* outp = (float*)d_out;

    scan_kernel<<<NPAIR, 64, 0, stream>>>(tm, ctid, cdrid, bct, brt,
                                          trowL, pidxL, vcnt);

    prep_kernel<<<CHUNK_BLOCKS + PM, 256, 0, stream>>>(
        W1, W2, W1b, W2b, outp, X, trowL, pidxL, vcnt, rows_dst, count, Xg);

    dim3 g1(PM / 32, C_HID / 128, KSPLIT);          // 96 x 6 x 2
    gemm1_kernel<<<g1, 256, 0, stream>>>(Xg, W1b, count, P);

    reduce1_kernel<<<(PM * C_HID / 4) / 256, 256, 0, stream>>>(P, b1, count, H);

    dim3 g2(PM / 32, C_OUT / 128);                  // 96 x 3
    gemm2_kernel<<<g2, 256, 0, stream>>>(H, W2b, b2, rows_dst, count, scale, outp);
}

// Round 17
// 123.105 us; speedup vs baseline: 1.1127x; 1.1127x over previous
//
#include <hip/hip_runtime.h>
#include <hip/hip_bf16.h>
#include <math.h>

typedef __bf16 bf16_t;
typedef bf16_t bf16x8 __attribute__((ext_vector_type(8)));
typedef bf16_t bf16x4 __attribute__((ext_vector_type(4)));
typedef float f32x4 __attribute__((ext_vector_type(4)));

#define L_TEXT 2048
#define N_TOKEN 2048
#define C_TEXT 3584
#define C_OUT 384
#define C_HID 768
#define BATCH 8
#define MAXROWS (BATCH * N_TOKEN)
#define PM 3072            // capacity for compacted rows (count ~2400)
#define NPAIR (BATCH * 6)
#define KSPLIT 4
#define KCHUNK (C_TEXT / KSPLIT)   // 896

#define NW1 (C_HID * C_TEXT / 8)          // 344064 W1 cvt chunks
#define NW2 (C_OUT * C_HID / 8)           // 36864  W2 cvt chunks
#define NZERO (MAXROWS * C_OUT / 4)       // 1572864 f32x4 zero chunks of d_out
#define CHUNKS_TOTAL (NW1 + NW2 + NZERO)
#define CHUNK_BLOCKS (CHUNKS_TOTAL / 256) // 7632 exactly
#define GCH (C_TEXT / 8)                  // 448 bf16x8 chunks per row

// ---------------------------------------------------------------------------
// init node: W1/W2 fp32->bf16 + zero d_out + 48 per-pair mask-scan blocks
__global__ __launch_bounds__(256) void init_map_kernel(
    const float* __restrict__ W1, const float* __restrict__ W2,
    bf16_t* __restrict__ W1b, bf16_t* __restrict__ W2b,
    float* __restrict__ outp,
    const int* __restrict__ tm, const int* __restrict__ ctid,
    const int* __restrict__ cdrid, const int* __restrict__ bct,
    const int* __restrict__ brt,
    int* __restrict__ trowL, int* __restrict__ pidxL, int* __restrict__ vcnt) {
    if (blockIdx.x >= CHUNK_BLOCKS) {
        const int bp = blockIdx.x - CHUNK_BLOCKS;
        const int lane = threadIdx.x;
        if (lane >= 64) return;
        const int b = bp / 6, p = bp % 6;
        const int ct = (p < 3) ? 1 : 2;
        const int rt = 2 + 2 * (p % 3);
        const unsigned long long ltm = (1ull << lane) - 1ull;

        unsigned int tbits = 0, pbits = 0;
#pragma unroll
        for (int i = 0; i < 32; i++) {
            int l = i * 64 + lane;
            unsigned int m = (ctid[b * L_TEXT + l] == ct) &&
                             (cdrid[b * L_TEXT + l] == rt) &&
                             (tm[b * L_TEXT + l] != 0);
            tbits |= m << i;
        }
#pragma unroll
        for (int i = 0; i < 32; i++) {
            int n = i * 64 + lane;
            unsigned int m = (bct[b * N_TOKEN + n] == ct) &&
                             (brt[b * N_TOKEN + n] == rt);
            pbits |= m << i;
        }
        int base = 0;
#pragma unroll
        for (int i = 0; i < 32; i++) {
            bool m = (tbits >> i) & 1;
            unsigned long long bal = __ballot(m);
            if (m) trowL[bp * L_TEXT + base + __popcll(bal & ltm)] = i * 64 + lane;
            base += __popcll(bal);
        }
        const int n_text = base;
        base = 0;
#pragma unroll
        for (int i = 0; i < 32; i++) {
            bool m = (pbits >> i) & 1;
            unsigned long long bal = __ballot(m);
            if (m) pidxL[bp * L_TEXT + base + __popcll(bal & ltm)] = i * 64 + lane;
            base += __popcll(bal);
        }
        const int n_prot = base;
        if (lane == 0) vcnt[bp] = n_text < n_prot ? n_text : n_prot;
        return;
    }
    int idx = blockIdx.x * 256 + threadIdx.x;
    if (idx < NW1) {
        int i = idx * 8;
        float4 v0 = *(const float4*)(W1 + i);
        float4 v1 = *(const float4*)(W1 + i + 4);
        bf16x8 o;
        o[0] = (bf16_t)v0.x; o[1] = (bf16_t)v0.y; o[2] = (bf16_t)v0.z; o[3] = (bf16_t)v0.w;
        o[4] = (bf16_t)v1.x; o[5] = (bf16_t)v1.y; o[6] = (bf16_t)v1.z; o[7] = (bf16_t)v1.w;
        *(bf16x8*)(W1b + i) = o;
    } else if (idx < NW1 + NW2) {
        int i = (idx - NW1) * 8;
        float4 v0 = *(const float4*)(W2 + i);
        float4 v1 = *(const float4*)(W2 + i + 4);
        bf16x8 o;
        o[0] = (bf16_t)v0.x; o[1] = (bf16_t)v0.y; o[2] = (bf16_t)v0.z; o[3] = (bf16_t)v0.w;
        o[4] = (bf16_t)v1.x; o[5] = (bf16_t)v1.y; o[6] = (bf16_t)v1.z; o[7] = (bf16_t)v1.w;
        *(bf16x8*)(W2b + i) = o;
    } else {
        int z = idx - NW1 - NW2;
        f32x4 zv = (f32x4){0.f, 0.f, 0.f, 0.f};
        *(f32x4*)(outp + (size_t)z * 4) = zv;
    }
}

// ---------------------------------------------------------------------------
// WIDE fused map+gather: one block per compacted row m. Each block caches the
// 48 vcnt's in LDS, derives (pair, rank) for m, writes rows_dst[m]+count, and
// copies/converts its X row into Xg. No atomics; width preserved (PM blocks).
__global__ __launch_bounds__(256) void gathermap_kernel(
    const float* __restrict__ X,
    const int* __restrict__ trowL, const int* __restrict__ pidxL,
    const int* __restrict__ vcnt,
    int* __restrict__ rows_dst, int* __restrict__ count,
    bf16_t* __restrict__ Xg) {
    __shared__ int vc[NPAIR];
    const int m = blockIdx.x;
    const int t = threadIdx.x;
    if (t < NPAIR) vc[t] = vcnt[t];
    __syncthreads();

    int base = 0, bp = -1, total = 0;
    for (int q = 0; q < NPAIR; q++) {
        int v = vc[q];
        if (bp < 0 && m < base + v) bp = q;       // first pair containing m
        if (bp < 0) base += v;
        total += v;
    }
    if (m == 0 && t == 0) *count = total < PM ? total : PM;
    if (bp < 0 || m >= PM) return;                // m beyond total rows
    const int r = m - base;
    const int b = bp / 6;

    if (t == 0) rows_dst[m] = b * N_TOKEN + pidxL[bp * L_TEXT + r];

    const int src = b * L_TEXT + trowL[bp * L_TEXT + r];
    const float* s = X + (size_t)src * C_TEXT;
    bf16_t* d = Xg + (size_t)m * C_TEXT;
    for (int c = t; c < GCH; c += 256) {
        int i = c * 8;
        float4 v0 = *(const float4*)(s + i);
        float4 v1 = *(const float4*)(s + i + 4);
        bf16x8 o;
        o[0] = (bf16_t)v0.x; o[1] = (bf16_t)v0.y; o[2] = (bf16_t)v0.z; o[3] = (bf16_t)v0.w;
        o[4] = (bf16_t)v1.x; o[5] = (bf16_t)v1.y; o[6] = (bf16_t)v1.z; o[7] = (bf16_t)v1.w;
        *(bf16x8*)(d + i) = o;
    }
}

// ---------------------------------------------------------------------------
// GEMM1 (split-K=4): P[ks][m][n] = sum_{k chunk} Xg[m][k]*W1[n][k]
// 128x128 tile, BK=32, 4 waves (2x2), 4x4 frags, reg-staged dbuf LDS. (R9)
__global__ __launch_bounds__(256) void gemm1_kernel(
    const bf16_t* __restrict__ Xg, const bf16_t* __restrict__ W1b,
    const int* __restrict__ countp, float* __restrict__ P) {
    int count = *countp; if (count > PM) count = PM;
    const int m0 = blockIdx.x * 128;
    if (m0 >= count) return;
    const int n0 = blockIdx.y * 128;
    const int kbeg = blockIdx.z * KCHUNK;

    __shared__ __align__(16) bf16_t As[2][128][40];
    __shared__ __align__(16) bf16_t Bs[2][128][40];

    const int t = threadIdx.x;
    const int lane = t & 63;
    const int w = t >> 6;
    const int wr = w >> 1, wc = w & 1;
    const int fr = lane & 15;
    const int kq = (lane >> 4) * 8;

    f32x4 acc[4][4];
#pragma unroll
    for (int i = 0; i < 4; i++)
#pragma unroll
        for (int j = 0; j < 4; j++) acc[i][j] = (f32x4){0.f, 0.f, 0.f, 0.f};

    const bf16_t* ap[2];
    const bf16_t* bp[2];
    int ofs[2];
#pragma unroll
    for (int j = 0; j < 2; j++) {
        int c = t + 256 * j;
        int row = c >> 2, c8 = (c & 3) * 8;
        ap[j] = Xg + (size_t)(m0 + row) * C_TEXT + kbeg + c8;
        bp[j] = W1b + (size_t)(n0 + row) * C_TEXT + kbeg + c8;
        ofs[j] = row * 40 + c8;
    }

    bf16_t* AsF = &As[0][0][0];
    bf16_t* BsF = &Bs[0][0][0];
    const int BUF = 128 * 40;

    bf16x8 ra[2], rb[2];
#pragma unroll
    for (int j = 0; j < 2; j++) { ra[j] = *(const bf16x8*)(ap[j]); rb[j] = *(const bf16x8*)(bp[j]); }

    const int T = KCHUNK / 32;   // 28
    for (int tile = 0; tile < T; ++tile) {
        const int cur = tile & 1;
#pragma unroll
        for (int j = 0; j < 2; j++) {
            *(bf16x8*)(AsF + cur * BUF + ofs[j]) = ra[j];
            *(bf16x8*)(BsF + cur * BUF + ofs[j]) = rb[j];
        }
        bf16x8 na[2], nb[2];
        bool more = (tile + 1 < T);
        if (more) {
            int k = (tile + 1) * 32;
#pragma unroll
            for (int j = 0; j < 2; j++) {
                na[j] = *(const bf16x8*)(ap[j] + k);
                nb[j] = *(const bf16x8*)(bp[j] + k);
            }
        }
        __syncthreads();
        bf16x8 af[4], bfr[4];
#pragma unroll
        for (int mi = 0; mi < 4; mi++)
            af[mi] = *(const bf16x8*)(AsF + cur * BUF + (wr * 64 + mi * 16 + fr) * 40 + kq);
#pragma unroll
        for (int ni = 0; ni < 4; ni++)
            bfr[ni] = *(const bf16x8*)(BsF + cur * BUF + (wc * 64 + ni * 16 + fr) * 40 + kq);
#pragma unroll
        for (int mi = 0; mi < 4; mi++)
#pragma unroll
            for (int ni = 0; ni < 4; ni++)
                acc[mi][ni] = __builtin_amdgcn_mfma_f32_16x16x32_bf16(
                    af[mi], bfr[ni], acc[mi][ni], 0, 0, 0);
        if (more) {
#pragma unroll
            for (int j = 0; j < 2; j++) { ra[j] = na[j]; rb[j] = nb[j]; }
        }
    }

    float* Pk = P + (size_t)blockIdx.z * PM * C_HID;
    const int rj = (lane >> 4) * 4;
#pragma unroll
    for (int mi = 0; mi < 4; mi++) {
#pragma unroll
        for (int ni = 0; ni < 4; ni++) {
            int gn = n0 + wc * 64 + ni * 16 + fr;
#pragma unroll
            for (int j = 0; j < 4; j++) {
                int gm = m0 + wr * 64 + mi * 16 + rj + j;
                if (gm < count) Pk[(size_t)gm * C_HID + gn] = acc[mi][ni][j];
            }
        }
    }
}

// ---------------------------------------------------------------------------
// reduce partials + bias + SiLU -> H (bf16)
__global__ __launch_bounds__(256) void reduce1_kernel(
    const float* __restrict__ P, const float* __restrict__ b1,
    const int* __restrict__ countp, bf16_t* __restrict__ H) {
    int count = *countp; if (count > PM) count = PM;
    int idx = blockIdx.x * 256 + threadIdx.x;
    int m = idx / (C_HID / 4);
    int c = (idx % (C_HID / 4)) * 4;
    if (m >= count) return;
    f32x4 s = *(const f32x4*)(P + (size_t)m * C_HID + c);
#pragma unroll
    for (int ks = 1; ks < KSPLIT; ks++)
        s += *(const f32x4*)(P + ((size_t)ks * PM + m) * C_HID + c);
    f32x4 bb = *(const f32x4*)(b1 + c);
    bf16x4 o;
#pragma unroll
    for (int j = 0; j < 4; j++) {
        float v = s[j] + bb[j];
        o[j] = (bf16_t)(v / (1.0f + __expf(-v)));
    }
    *(bf16x4*)(H + (size_t)m * C_HID + c) = o;
}

// ---------------------------------------------------------------------------
// GEMM2 fused: out[rows_dst[m]][n] = scale*(sum_K H[m][k]*W2[n][k] + b2[n])
// 32x128 tile, BK=32, 4 waves (1x4), wave tile 32x32, dbuf LDS. (proven)
__global__ __launch_bounds__(256) void gemm2_kernel(
    const bf16_t* __restrict__ Hm, const bf16_t* __restrict__ W2b,
    const float* __restrict__ b2, const int* __restrict__ rows_dst,
    const int* __restrict__ countp, const float* __restrict__ scale,
    float* __restrict__ outp) {
    int count = *countp; if (count > PM) count = PM;
    const int m0 = blockIdx.x * 32;
    if (m0 >= count) return;
    const int n0 = blockIdx.y * 128;

    __shared__ __align__(16) bf16_t As[2][32][40];
    __shared__ __align__(16) bf16_t Bs[2][128][40];

    const int t = threadIdx.x;
    const int lane = t & 63;
    const int w = t >> 6;              // wave n-offset = w*32
    const int fr = lane & 15;
    const int kq = (lane >> 4) * 8;

    f32x4 acc[2][2];
#pragma unroll
    for (int i = 0; i < 2; i++)
#pragma unroll
        for (int j = 0; j < 2; j++) acc[i][j] = (f32x4){0.f, 0.f, 0.f, 0.f};

    const int arow = t >> 2, ac8 = (t & 3) * 8;
    const bool astage = (t < 128);
    const bf16_t* ap = Hm + (size_t)(m0 + arow) * C_HID + ac8;   // stale rows harmless
    const int aofs = arow * 40 + ac8;
    const bf16_t* bp[2];
    int bofs[2];
#pragma unroll
    for (int j = 0; j < 2; j++) {
        int c = t + 256 * j;
        int row = c >> 2, c8 = (c & 3) * 8;
        bp[j] = W2b + (size_t)(n0 + row) * C_HID + c8;
        bofs[j] = row * 40 + c8;
    }

    bf16_t* AsF = &As[0][0][0];
    bf16_t* BsF = &Bs[0][0][0];
    const int ABUF = 32 * 40, BBUF = 128 * 40;

    bf16x8 ra;
    if (astage) ra = *(const bf16x8*)(ap);
    bf16x8 rb0 = *(const bf16x8*)(bp[0]);
    bf16x8 rb1 = *(const bf16x8*)(bp[1]);

    const int T = C_HID / 32;   // 24
    for (int tile = 0; tile < T; ++tile) {
        const int cur = tile & 1;
        if (astage) *(bf16x8*)(AsF + cur * ABUF + aofs) = ra;
        *(bf16x8*)(BsF + cur * BBUF + bofs[0]) = rb0;
        *(bf16x8*)(BsF + cur * BBUF + bofs[1]) = rb1;
        bf16x8 na, nb0, nb1;
        bool more = (tile + 1 < T);
        if (more) {
            int k = (tile + 1) * 32;
            if (astage) na = *(const bf16x8*)(ap + k);
            nb0 = *(const bf16x8*)(bp[0] + k);
            nb1 = *(const bf16x8*)(bp[1] + k);
        }
        __syncthreads();
        bf16x8 af[2], bfr[2];
#pragma unroll
        for (int mi = 0; mi < 2; mi++)
            af[mi] = *(const bf16x8*)(AsF + cur * ABUF + (mi * 16 + fr) * 40 + kq);
#pragma unroll
        for (int ni = 0; ni < 2; ni++)
            bfr[ni] = *(const bf16x8*)(BsF + cur * BBUF + (w * 32 + ni * 16 + fr) * 40 + kq);
#pragma unroll
        for (int mi = 0; mi < 2; mi++)
#pragma unroll
            for (int ni = 0; ni < 2; ni++)
                acc[mi][ni] = __builtin_amdgcn_mfma_f32_16x16x32_bf16(
                    af[mi], bfr[ni], acc[mi][ni], 0, 0, 0);
        if (more) { if (astage) ra = na; rb0 = nb0; rb1 = nb1; }
        __syncthreads();
    }

    const float sc = scale[0];
    const int rj = (lane >> 4) * 4;
#pragma unroll
    for (int mi = 0; mi < 2; mi++) {
#pragma unroll
        for (int ni = 0; ni < 2; ni++) {
            int gn = n0 + w * 32 + ni * 16 + fr;
            float bias = b2[gn];
#pragma unroll
            for (int j = 0; j < 4; j++) {
                int gm = m0 + mi * 16 + rj + j;
                if (gm < count) {
                    int dst = rows_dst[gm];
                    outp[(size_t)dst * C_OUT + gn] = sc * (acc[mi][ni][j] + bias);
                }
            }
        }
    }
}

// ---------------------------------------------------------------------------
extern "C" void kernel_launch(void* const* d_in, const int* in_sizes, int n_in,
                              void* d_out, int out_size, void* d_ws, size_t ws_size,
                              hipStream_t stream) {
    const float* X     = (const float*)d_in[0];
    const int*   tm    = (const int*)d_in[1];
    const int*   ctid  = (const int*)d_in[2];
    const int*   cdrid = (const int*)d_in[3];
    const int*   bct   = (const int*)d_in[4];
    const int*   brt   = (const int*)d_in[5];
    const float* W1    = (const float*)d_in[6];
    const float* b1    = (const float*)d_in[7];
    const float* W2    = (const float*)d_in[8];
    const float* b2    = (const float*)d_in[9];
    const float* scale = (const float*)d_in[10];

    char* ws = (char*)d_ws;
    size_t off = 0;
    int* count = (int*)(ws + off);        off += 1024;
    int* vcnt = (int*)(ws + off);         off += 1024;
    int* rows_dst = (int*)(ws + off);     off += (size_t)PM * 4;
    int* trowL = (int*)(ws + off);        off += (size_t)NPAIR * L_TEXT * 4;
    int* pidxL = (int*)(ws + off);        off += (size_t)NPAIR * L_TEXT * 4;
    bf16_t* W1b = (bf16_t*)(ws + off);    off += (size_t)C_HID * C_TEXT * 2;
    bf16_t* W2b = (bf16_t*)(ws + off);    off += (size_t)C_OUT * C_HID * 2;
    bf16_t* Xg = (bf16_t*)(ws + off);     off += (size_t)PM * C_TEXT * 2;
    bf16_t* H = (bf16_t*)(ws + off);      off += (size_t)PM * C_HID * 2;
    float* P = (float*)(ws + off);        off += (size_t)KSPLIT * PM * C_HID * 4;
    float* outp = (float*)d_out;

    init_map_kernel<<<CHUNK_BLOCKS + NPAIR, 256, 0, stream>>>(
        W1, W2, W1b, W2b, outp, tm, ctid, cdrid, bct, brt, trowL, pidxL, vcnt);

    gathermap_kernel<<<PM, 256, 0, stream>>>(X, trowL, pidxL, vcnt,
                                             rows_dst, count, Xg);

    dim3 g1(PM / 128, C_HID / 128, KSPLIT);         // 24 x 6 x 4
    gemm1_kernel<<<g1, 256, 0, stream>>>(Xg, W1b, count, P);

    reduce1_kernel<<<(PM * C_HID / 4) / 256, 256, 0, stream>>>(P, b1, count, H);

    dim3 g2(PM / 32, C_OUT / 128);                  // 96 x 3
    gemm2_kernel<<<g2, 256, 0, stream>>>(H, W2b, b2, rows_dst, count, scale, outp);
}